// Round 1
// baseline (182.913 us; speedup 1.0000x reference)
//
#include <hip/hip_runtime.h>

#define LN 1024      // leaves
#define FF 128
#define HH 128
#define CC 10
#define NNODES 2047
#define DD 34314
#define DEPTH 11

#define OFF_W0 0
#define OFF_B0 16384
#define OFF_W1 16512
#define OFF_B1 32896
#define OFF_W2 33024
#define OFF_B2 34304

// ---------------- Kernel A: delta = sum(W[0]^2) + sum_{i>=1} l1(W[i]) / mut[i] ----------------
__global__ __launch_bounds__(256) void delta_kernel(const float* __restrict__ W,
                                                    const float* __restrict__ heights,
                                                    float* __restrict__ delta_out) {
    const int node = blockIdx.x;
    const float2* row2 = reinterpret_cast<const float2*>(W + (size_t)node * DD);
    const int n2 = DD / 2;  // 17157, rows are 8B-aligned (DD*4 % 8 == 0)

    float absacc = 0.f, sqacc = 0.f;
    for (int i = threadIdx.x; i < n2; i += 256) {
        float2 v = row2[i];
        absacc += fabsf(v.x) + fabsf(v.y);
        sqacc  += v.x * v.x + v.y * v.y;
    }

    // wave (64-lane) shuffle reduce, then cross-wave via LDS
    for (int o = 32; o > 0; o >>= 1) {
        absacc += __shfl_down(absacc, o);
        sqacc  += __shfl_down(sqacc, o);
    }
    __shared__ float redA[4], redS[4];
    const int lane = threadIdx.x & 63;
    const int wid  = threadIdx.x >> 6;
    if (lane == 0) { redA[wid] = absacc; redS[wid] = sqacc; }
    __syncthreads();
    if (threadIdx.x == 0) {
        float a = redA[0] + redA[1] + redA[2] + redA[3];
        float s = redS[0] + redS[1] + redS[2] + redS[3];
        if (node == 0) {
            atomicAdd(delta_out, s);
        } else {
            const int p = (node - 1) >> 1;
            float mut = fabsf(heights[node] - heights[p]);
            mut = fmaxf(mut, 1e-7f);
            atomicAdd(delta_out, a / mut);
        }
    }
}

// ---------------- Kernel B: per-leaf MLP on effective (ancestor-summed) weights ----------------
__global__ __launch_bounds__(256) void mlp_kernel(const float* __restrict__ W,
                                                  const float* __restrict__ x,
                                                  float* __restrict__ out) {
    const int leaf = blockIdx.x;
    const int node = (LN - 1) + leaf;

    int anc[DEPTH];
    {
        int nn = node;
#pragma unroll
        for (int k = 0; k < DEPTH; ++k) { anc[k] = nn; nn = (nn - 1) >> 1; }
    }

    __shared__ float Ws[FF * HH];   // 64 KB, reused for W0 / W1 / W2
    __shared__ float xs[FF];
    __shared__ float bs[HH];
    __shared__ float h0s[HH];
    __shared__ float h1s[HH];
    __shared__ float logit[CC];

    const int tid = threadIdx.x;

    if (tid < FF) xs[tid] = x[leaf * FF + tid];

    // ---- stage effective W0 (F*H) + b0 ----
    if (tid < HH) {
        float s = 0.f;
#pragma unroll
        for (int k = 0; k < DEPTH; ++k) s += W[(size_t)anc[k] * DD + OFF_B0 + tid];
        bs[tid] = s;
    }
    for (int idx = tid; idx < FF * HH; idx += 256) {
        float s = 0.f;
#pragma unroll
        for (int k = 0; k < DEPTH; ++k) s += W[(size_t)anc[k] * DD + OFF_W0 + idx];
        Ws[idx] = s;
    }
    __syncthreads();

    // ---- layer 0: h0 = relu(x . W0 + b0) ----
    if (tid < HH) {
        float acc = bs[tid];
        for (int f = 0; f < FF; ++f) acc += xs[f] * Ws[f * HH + tid];
        h0s[tid] = fmaxf(acc, 0.f);
    }
    __syncthreads();

    // ---- stage effective W1 (H*H) + b1 ----
    if (tid < HH) {
        float s = 0.f;
#pragma unroll
        for (int k = 0; k < DEPTH; ++k) s += W[(size_t)anc[k] * DD + OFF_B1 + tid];
        bs[tid] = s;
    }
    for (int idx = tid; idx < HH * HH; idx += 256) {
        float s = 0.f;
#pragma unroll
        for (int k = 0; k < DEPTH; ++k) s += W[(size_t)anc[k] * DD + OFF_W1 + idx];
        Ws[idx] = s;
    }
    __syncthreads();

    // ---- layer 1: h1 = relu(h0 . W1 + b1) ----
    if (tid < HH) {
        float acc = bs[tid];
        for (int h = 0; h < HH; ++h) acc += h0s[h] * Ws[h * HH + tid];
        h1s[tid] = fmaxf(acc, 0.f);
    }
    __syncthreads();

    // ---- stage effective W2 (H*C) + b2 ----
    for (int idx = tid; idx < HH * CC; idx += 256) {
        float s = 0.f;
#pragma unroll
        for (int k = 0; k < DEPTH; ++k) s += W[(size_t)anc[k] * DD + OFF_W2 + idx];
        Ws[idx] = s;
    }
    if (tid < CC) {
        float s = 0.f;
#pragma unroll
        for (int k = 0; k < DEPTH; ++k) s += W[(size_t)anc[k] * DD + OFF_B2 + tid];
        bs[tid] = s;
    }
    __syncthreads();

    // ---- layer 2 logits + softmax ----
    if (tid < CC) {
        float acc = bs[tid];
        for (int h = 0; h < HH; ++h) acc += h1s[h] * Ws[h * CC + tid];
        logit[tid] = acc;
    }
    __syncthreads();
    if (tid == 0) {
        float m = logit[0];
#pragma unroll
        for (int c = 1; c < CC; ++c) m = fmaxf(m, logit[c]);
        float e[CC];
        float sum = 0.f;
#pragma unroll
        for (int c = 0; c < CC; ++c) { e[c] = expf(logit[c] - m); sum += e[c]; }
        const float inv = 1.f / sum;
#pragma unroll
        for (int c = 0; c < CC; ++c) out[leaf * CC + c] = e[c] * inv;
    }
}

extern "C" void kernel_launch(void* const* d_in, const int* in_sizes, int n_in,
                              void* d_out, int out_size, void* d_ws, size_t ws_size,
                              hipStream_t stream) {
    const float* x       = (const float*)d_in[0];   // (1024, 128)
    const float* W       = (const float*)d_in[1];   // (2047, 34314)
    const float* heights = (const float*)d_in[2];   // (2047,)
    // d_in[3] = parent (int32), d_in[4] = leaf_idx (int32) — recomputed in-kernel

    float* out   = (float*)d_out;              // [0 .. 10239] softmax probs
    float* delta = (float*)d_out + LN * CC;    // [10240] scalar delta

    // zero the atomic accumulator (graph-capture legal)
    hipMemsetAsync(delta, 0, sizeof(float), stream);

    delta_kernel<<<NNODES, 256, 0, stream>>>(W, heights, delta);
    mlp_kernel<<<LN, 256, 0, stream>>>(W, x, out);
}

// Round 2
// 141.312 us; speedup vs baseline: 1.2944x; 1.2944x over previous
//
#include <hip/hip_runtime.h>

#define LN 1024
#define FF 128
#define HH 128
#define CC 10
#define NNODES 2047
#define DD 34314
#define DD2 17157          // DD/2
#define OFF_W0 0
#define OFF_B0 16384
#define OFF_W1 16512
#define OFF_B1 32896
#define OFF_W2 33024
#define OFF_B2 34304
#define CHUNK2 4290        // ceil(DD2 / 4)

__global__ void init_delta(float* delta) { *delta = 0.f; }

// ---------------- K1: materialize eff8 (sum of levels 0..8 along each path) into ws,
// ----------------     fused delta for levels 0..8 (owner blocks) ----------------
__global__ __launch_bounds__(256) void eff8_delta_kernel(const float* __restrict__ W,
                                                         const float* __restrict__ heights,
                                                         float* __restrict__ ws,
                                                         float* __restrict__ delta_out) {
    const int m     = blockIdx.x >> 2;   // level-8 node index within level, 0..255
    const int chunk = blockIdx.x & 3;

    int path[9];
    {
        int n = 255 + m;
#pragma unroll
        for (int k = 0; k < 9; ++k) { path[k] = n; n = (n - 1) >> 1; }
    }
    const float2* rp[9];
#pragma unroll
    for (int k = 0; k < 9; ++k) rp[k] = reinterpret_cast<const float2*>(W + (size_t)path[k] * DD);
    float2* wrow = reinterpret_cast<float2*>(ws + (size_t)m * DD);

    const int lo = chunk * CHUNK2;
    const int hi = min(lo + CHUNK2, DD2);

    float acc[9];
#pragma unroll
    for (int k = 0; k < 9; ++k) acc[k] = 0.f;

#pragma unroll 2
    for (int i = lo + (int)threadIdx.x; i < hi; i += 256) {
        float sx = 0.f, sy = 0.f;
#pragma unroll
        for (int k = 0; k < 9; ++k) {
            float2 w = rp[k][i];
            sx += w.x; sy += w.y;
            if (k == 8) acc[k] += w.x * w.x + w.y * w.y;   // node 0: sum of squares
            else        acc[k] += fabsf(w.x) + fabsf(w.y);
        }
        wrow[i] = make_float2(sx, sy);
    }

    __shared__ float red[4];
    const int lane = threadIdx.x & 63, wid = threadIdx.x >> 6;
#pragma unroll
    for (int k = 0; k < 9; ++k) {
        const bool owner = (m & ((1 << k) - 1)) == 0;   // block-uniform
        if (!owner) continue;
        float v = acc[k];
        for (int o = 32; o > 0; o >>= 1) v += __shfl_down(v, o);
        if (lane == 0) red[wid] = v;
        __syncthreads();
        if (threadIdx.x == 0) {
            float t = red[0] + red[1] + red[2] + red[3];
            const int node = path[k];
            if (node == 0) {
                atomicAdd(delta_out, t);
            } else {
                float mut = fmaxf(fabsf(heights[node] - heights[(node - 1) >> 1]), 1e-7f);
                atomicAdd(delta_out, t / mut);
            }
        }
        __syncthreads();
    }
}

// ---------------- K2: per-leaf MLP via distributive matvec over {eff8, level9, leaf},
// ----------------     fused delta for level-9 (even leaf) and leaf rows ----------------
__global__ __launch_bounds__(256) void mlp_kernel(const float* __restrict__ W,
                                                  const float* __restrict__ ws,
                                                  const float* __restrict__ x,
                                                  const float* __restrict__ heights,
                                                  float* __restrict__ out,
                                                  float* __restrict__ delta_out) {
    const int leaf = blockIdx.x;
    const int node = (LN - 1) + leaf;       // level-10
    const int n9   = (node - 1) >> 1;       // level-9 ancestor
    const int m8   = leaf >> 2;             // ws row index (level-8 ancestor)

    const float* Er = ws + (size_t)m8 * DD;
    const float* Ar = W  + (size_t)n9 * DD;
    const float* Br = W  + (size_t)node * DD;

    const int tid = threadIdx.x;
    __shared__ float ins[HH];        // current layer input (x, then h0, then h1)
    __shared__ float part[4 * HH];   // matvec partials
    __shared__ float lg[CC];
    __shared__ float redA[4], redB[4];

    if (tid < FF) ins[tid] = x[leaf * FF + tid];
    float absA = 0.f, absB = 0.f;
    __syncthreads();

    const int j2 = tid & 63;   // column pair {2*j2, 2*j2+1}
    const int fq = tid >> 6;   // input quarter

    // ---------- layers 0 and 1 (IN=128 -> OUT=128) ----------
#pragma unroll
    for (int layer = 0; layer < 2; ++layer) {
        const int offW = layer ? OFF_W1 : OFF_W0;
        const int offB = layer ? OFF_B1 : OFF_B0;
        const float2* Ew = reinterpret_cast<const float2*>(Er + offW);
        const float2* Aw = reinterpret_cast<const float2*>(Ar + offW);
        const float2* Bw = reinterpret_cast<const float2*>(Br + offW);
        float ax = 0.f, ay = 0.f;
#pragma unroll 4
        for (int i = 0; i < 32; ++i) {
            const int f = fq * 32 + i;
            const float xv = ins[f];
            float2 we = Ew[f * 64 + j2];
            float2 wa = Aw[f * 64 + j2];
            float2 wb = Bw[f * 64 + j2];
            ax += xv * (we.x + wa.x + wb.x);
            ay += xv * (we.y + wa.y + wb.y);
            absA += fabsf(wa.x) + fabsf(wa.y);
            absB += fabsf(wb.x) + fabsf(wb.y);
        }
        part[fq * HH + 2 * j2]     = ax;
        part[fq * HH + 2 * j2 + 1] = ay;
        __syncthreads();
        if (tid < HH) {
            float be = Er[offB + tid], ba = Ar[offB + tid], bb = Br[offB + tid];
            absA += fabsf(ba);
            absB += fabsf(bb);
            float h = part[tid] + part[HH + tid] + part[2 * HH + tid] + part[3 * HH + tid]
                      + (be + ba + bb);
            ins[tid] = fmaxf(h, 0.f);
        }
        __syncthreads();
    }

    // ---------- layer 2 (IN=128 -> OUT=10) ----------
    {
        const int c = tid & 15;
        const int g = tid >> 4;    // 16 groups x 8 h each
        float accv = 0.f;
#pragma unroll
        for (int i = 0; i < 8; ++i) {
            const int h = g * 8 + i;
            const float hv = ins[h];
            if (c < CC) {
                float we = Er[OFF_W2 + h * CC + c];
                float wa = Ar[OFF_W2 + h * CC + c];
                float wb = Br[OFF_W2 + h * CC + c];
                accv += hv * (we + wa + wb);
                absA += fabsf(wa);
                absB += fabsf(wb);
            }
        }
        part[tid] = accv;   // reuse as [16][16]
        __syncthreads();
        if (tid < CC) {
            float s = 0.f;
#pragma unroll
            for (int g2 = 0; g2 < 16; ++g2) s += part[g2 * 16 + tid];
            float be = Er[OFF_B2 + tid], ba = Ar[OFF_B2 + tid], bb = Br[OFF_B2 + tid];
            absA += fabsf(ba);
            absB += fabsf(bb);
            lg[tid] = s + (be + ba + bb);
        }
        __syncthreads();
    }

    // ---------- softmax ----------
    if (tid == 0) {
        float mx = lg[0];
#pragma unroll
        for (int c2 = 1; c2 < CC; ++c2) mx = fmaxf(mx, lg[c2]);
        float e[CC], s = 0.f;
#pragma unroll
        for (int c2 = 0; c2 < CC; ++c2) { e[c2] = expf(lg[c2] - mx); s += e[c2]; }
        const float inv = 1.f / s;
#pragma unroll
        for (int c2 = 0; c2 < CC; ++c2) out[leaf * CC + c2] = e[c2] * inv;
    }

    // ---------- delta contributions (leaf row always; level-9 row if even leaf) ----------
    for (int o = 32; o > 0; o >>= 1) {
        absA += __shfl_down(absA, o);
        absB += __shfl_down(absB, o);
    }
    const int lane = tid & 63, wid = tid >> 6;
    if (lane == 0) { redA[wid] = absA; redB[wid] = absB; }
    __syncthreads();
    if (tid == 0) {
        float a = redA[0] + redA[1] + redA[2] + redA[3];
        float b = redB[0] + redB[1] + redB[2] + redB[3];
        const int n8 = (n9 - 1) >> 1;
        float mutB = fmaxf(fabsf(heights[node] - heights[n9]), 1e-7f);
        float contrib = b / mutB;
        if ((leaf & 1) == 0) {
            float mutA = fmaxf(fabsf(heights[n9] - heights[n8]), 1e-7f);
            contrib += a / mutA;
        }
        atomicAdd(delta_out, contrib);
    }
}

extern "C" void kernel_launch(void* const* d_in, const int* in_sizes, int n_in,
                              void* d_out, int out_size, void* d_ws, size_t ws_size,
                              hipStream_t stream) {
    const float* x       = (const float*)d_in[0];   // (1024, 128)
    const float* W       = (const float*)d_in[1];   // (2047, 34314)
    const float* heights = (const float*)d_in[2];   // (2047,)

    float* out   = (float*)d_out;
    float* delta = (float*)d_out + LN * CC;
    float* ws    = (float*)d_ws;                    // 256 * 34314 * 4 B = 35.1 MB

    init_delta<<<1, 1, 0, stream>>>(delta);
    eff8_delta_kernel<<<256 * 4, 256, 0, stream>>>(W, heights, ws, delta);
    mlp_kernel<<<LN, 256, 0, stream>>>(W, ws, x, heights, out, delta);
}

// Round 3
// 130.002 us; speedup vs baseline: 1.4070x; 1.0870x over previous
//
#include <hip/hip_runtime.h>

#define LN 1024
#define FF 128
#define HH 128
#define CC 10
#define DD 34314
#define OFF_W0 0
#define OFF_B0 16384
#define OFF_W1 16512
#define OFF_B1 32896
#define OFF_W2 33024
#define OFF_B2 34304

__global__ void init_delta(float* delta) { *delta = 0.f; }

// One block = 4 sibling leaves (one level-8 subtree). 15 row-streams:
//   R[0..8] = level-8 ancestor .. root (shared by all 4 leaves)
//   R[9..10] = the two level-9 nodes, R[11..14] = the four leaf nodes.
// Distributive matvec: y_q = x_q . (sum_k R_k) = sum over streams, combined per element.
// Delta fused: accR[r] accumulates l1 (r=8 -> root, squared); owner-gated atomics.
__global__ __launch_bounds__(512) void fused_kernel(const float* __restrict__ W,
                                                    const float* __restrict__ x,
                                                    const float* __restrict__ heights,
                                                    float* __restrict__ out,
                                                    float* __restrict__ delta_out) {
    const int m    = blockIdx.x;        // 0..255 : level-8 node = 255+m
    const int tid  = threadIdx.x;
    const int lane = tid & 63;
    const int wv   = tid >> 6;          // wave id == f-eighth (16 f each)
    const int j2   = lane;              // column pair (2*j2, 2*j2+1)

    int path[9];
    {
        int n = 255 + m;
#pragma unroll
        for (int k = 0; k < 9; ++k) { path[k] = n; n = (n - 1) >> 1; }
    }
    const float* R[15];
#pragma unroll
    for (int k = 0; k < 9; ++k) R[k] = W + (size_t)path[k] * DD;
    R[9]  = W + (size_t)(511 + 2 * m) * DD;
    R[10] = W + (size_t)(512 + 2 * m) * DD;
#pragma unroll
    for (int q = 0; q < 4; ++q) R[11 + q] = W + (size_t)(1023 + 4 * m + q) * DD;

    __shared__ float ins[4][HH];        // current layer input per leaf
    __shared__ float part[4][8][HH];    // matvec partials [leaf][wave][col]
    __shared__ float lgts[4][CC];
    __shared__ float red[15][8];

    // stage x; zero logits
    if (tid < 512) {
        const int q = tid >> 7, t = tid & 127;
        ins[q][t] = x[(4 * m + q) * FF + t];
    }
    if (tid < 4 * CC) ((float*)lgts)[tid] = 0.f;

    float accR[15];
#pragma unroll
    for (int r = 0; r < 15; ++r) accR[r] = 0.f;

    __syncthreads();

    // ---------------- layers 0 and 1 (128 -> 128) ----------------
#pragma unroll
    for (int layer = 0; layer < 2; ++layer) {
        const int offW = layer ? OFF_W1 : OFF_W0;
        const int offB = layer ? OFF_B1 : OFF_B0;
        const float2* S2[15];
#pragma unroll
        for (int r = 0; r < 15; ++r) S2[r] = reinterpret_cast<const float2*>(R[r] + offW);

        float yx[4], yy[4];
#pragma unroll
        for (int q = 0; q < 4; ++q) { yx[q] = 0.f; yy[q] = 0.f; }

#pragma unroll 2
        for (int i = 0; i < 16; ++i) {
            const int f   = (wv << 4) + i;
            const int off = f * 64 + j2;
            float ex = 0.f, ey = 0.f;
#pragma unroll
            for (int k = 0; k < 9; ++k) {
                const float2 w = S2[k][off];
                ex += w.x; ey += w.y;
                if (k == 8) accR[8] += w.x * w.x + w.y * w.y;
                else        accR[k] += fabsf(w.x) + fabsf(w.y);
            }
            const float2 wa0 = S2[9][off];
            const float2 wa1 = S2[10][off];
            accR[9]  += fabsf(wa0.x) + fabsf(wa0.y);
            accR[10] += fabsf(wa1.x) + fabsf(wa1.y);
#pragma unroll
            for (int q = 0; q < 4; ++q) {
                const float2 wb = S2[11 + q][off];
                accR[11 + q] += fabsf(wb.x) + fabsf(wb.y);
                const float2 wa = (q < 2) ? wa0 : wa1;
                const float xv = ins[q][f];
                yx[q] += xv * (ex + wa.x + wb.x);
                yy[q] += xv * (ey + wa.y + wb.y);
            }
        }
#pragma unroll
        for (int q = 0; q < 4; ++q)
            *reinterpret_cast<float2*>(&part[q][wv][2 * j2]) = make_float2(yx[q], yy[q]);
        __syncthreads();

        if (tid < HH) {
            float eb = 0.f;
#pragma unroll
            for (int k = 0; k < 9; ++k) {
                const float v = R[k][offB + tid];
                eb += v;
                if (k == 8) accR[8] += v * v; else accR[k] += fabsf(v);
            }
            const float a0 = R[9][offB + tid];
            const float a1 = R[10][offB + tid];
            accR[9]  += fabsf(a0);
            accR[10] += fabsf(a1);
            float hv[4];
#pragma unroll
            for (int q = 0; q < 4; ++q) {
                const float bq = R[11 + q][offB + tid];
                accR[11 + q] += fabsf(bq);
                float s = eb + ((q < 2) ? a0 : a1) + bq;
#pragma unroll
                for (int w = 0; w < 8; ++w) s += part[q][w][tid];
                hv[q] = fmaxf(s, 0.f);
            }
            __syncthreads();            // all reads of old ins done (pre-barrier above covers matvec)
#pragma unroll
            for (int q = 0; q < 4; ++q) ins[q][tid] = hv[q];
        } else {
            __syncthreads();
        }
        __syncthreads();
    }

    // ---------------- layer 2 (128 -> 10) ----------------
    {
        const float2* S2[15];
#pragma unroll
        for (int r = 0; r < 15; ++r) S2[r] = reinterpret_cast<const float2*>(R[r] + OFF_W2);
        for (int i = tid; i < 640; i += 512) {   // 640 float2 = 1280 floats
            const int h  = i / 5;
            const int c0 = 2 * (i - 5 * h);
            float ex = 0.f, ey = 0.f;
#pragma unroll
            for (int k = 0; k < 9; ++k) {
                const float2 w = S2[k][i];
                ex += w.x; ey += w.y;
                if (k == 8) accR[8] += w.x * w.x + w.y * w.y;
                else        accR[k] += fabsf(w.x) + fabsf(w.y);
            }
            const float2 wa0 = S2[9][i];
            const float2 wa1 = S2[10][i];
            accR[9]  += fabsf(wa0.x) + fabsf(wa0.y);
            accR[10] += fabsf(wa1.x) + fabsf(wa1.y);
#pragma unroll
            for (int q = 0; q < 4; ++q) {
                const float2 wb = S2[11 + q][i];
                accR[11 + q] += fabsf(wb.x) + fabsf(wb.y);
                const float2 wa = (q < 2) ? wa0 : wa1;
                const float hvv = ins[q][h];
                atomicAdd(&lgts[q][c0],     hvv * (ex + wa.x + wb.x));
                atomicAdd(&lgts[q][c0 + 1], hvv * (ey + wa.y + wb.y));
            }
        }
        __syncthreads();
        if (tid < CC) {
            float eb = 0.f;
#pragma unroll
            for (int k = 0; k < 9; ++k) {
                const float v = R[k][OFF_B2 + tid];
                eb += v;
                if (k == 8) accR[8] += v * v; else accR[k] += fabsf(v);
            }
            const float a0 = R[9][OFF_B2 + tid];
            const float a1 = R[10][OFF_B2 + tid];
            accR[9]  += fabsf(a0);
            accR[10] += fabsf(a1);
#pragma unroll
            for (int q = 0; q < 4; ++q) {
                const float bq = R[11 + q][OFF_B2 + tid];
                accR[11 + q] += fabsf(bq);
                lgts[q][tid] += eb + ((q < 2) ? a0 : a1) + bq;
            }
        }
        __syncthreads();
    }

    // ---------------- softmax (one thread per leaf) ----------------
    if (tid < 4) {
        const int q = tid;
        float mx = lgts[q][0];
#pragma unroll
        for (int c = 1; c < CC; ++c) mx = fmaxf(mx, lgts[q][c]);
        float e[CC], s = 0.f;
#pragma unroll
        for (int c = 0; c < CC; ++c) { e[c] = expf(lgts[q][c] - mx); s += e[c]; }
        const float inv = 1.f / s;
#pragma unroll
        for (int c = 0; c < CC; ++c) out[(4 * m + q) * CC + c] = e[c] * inv;
    }

    // ---------------- fused delta: reduce 15 per-row accumulators ----------------
#pragma unroll
    for (int r = 0; r < 15; ++r) {
        float v = accR[r];
        for (int o = 32; o > 0; o >>= 1) v += __shfl_down(v, o);
        if (lane == 0) red[r][wv] = v;
    }
    __syncthreads();
    if (tid == 0) {
        float tot[15];
#pragma unroll
        for (int r = 0; r < 15; ++r) {
            float s = 0.f;
#pragma unroll
            for (int w = 0; w < 8; ++w) s += red[r][w];
            tot[r] = s;
        }
        float contrib = 0.f;
        // levels 8..1 (path[0..7]) — owner: lowest-(k)-bits of m zero
#pragma unroll
        for (int k = 0; k < 8; ++k) {
            if ((m & ((1 << k) - 1)) == 0) {
                const float mut = fmaxf(fabsf(heights[path[k]] - heights[path[k + 1]]), 1e-7f);
                contrib += tot[k] / mut;
            }
        }
        if (m == 0) contrib += tot[8];  // root: sum of squares
        // level-9 nodes (unique to this block), parent = path[0]
        const float h8 = heights[path[0]];
#pragma unroll
        for (int j = 0; j < 2; ++j) {
            const int n9 = 511 + 2 * m + j;
            const float mut = fmaxf(fabsf(heights[n9] - h8), 1e-7f);
            contrib += tot[9 + j] / mut;
        }
        // leaves, parent = their level-9 node
#pragma unroll
        for (int q = 0; q < 4; ++q) {
            const int node = 1023 + 4 * m + q;
            const int n9   = 511 + 2 * m + (q >> 1);
            const float mut = fmaxf(fabsf(heights[node] - heights[n9]), 1e-7f);
            contrib += tot[11 + q] / mut;
        }
        atomicAdd(delta_out, contrib);
    }
}

extern "C" void kernel_launch(void* const* d_in, const int* in_sizes, int n_in,
                              void* d_out, int out_size, void* d_ws, size_t ws_size,
                              hipStream_t stream) {
    const float* x       = (const float*)d_in[0];   // (1024, 128)
    const float* W       = (const float*)d_in[1];   // (2047, 34314)
    const float* heights = (const float*)d_in[2];   // (2047,)

    float* out   = (float*)d_out;
    float* delta = (float*)d_out + LN * CC;

    init_delta<<<1, 1, 0, stream>>>(delta);
    fused_kernel<<<256, 512, 0, stream>>>(W, x, heights, out, delta);
}

// Round 4
// 97.076 us; speedup vs baseline: 1.8842x; 1.3392x over previous
//
#include <hip/hip_runtime.h>

#define LN 1024
#define FF 128
#define HH 128
#define CC 10
#define DD 34314
#define OFF_W0 0
#define OFF_B0 16384
#define OFF_W1 16512
#define OFF_B1 32896
#define OFF_W2 33024
#define OFF_B2 34304

__global__ void init_delta(float* delta) { *delta = 0.f; }

__device__ __forceinline__ float invmut(const float* h, int node, int par) {
    return 1.f / fmaxf(fabsf(h[node] - h[par]), 1e-7f);
}

// One block = one level-8 subtree (4 leaves), 1024 threads.
// 15 row-streams: R[0..8] = level-8 ancestor .. root, R[9..10] = level-9 pair,
// R[11..14] = 4 leaves. Distributive matvec; delta fully fused via per-stream
// weights wgt[r] (= owner ? 1/mut : 0), root sum-of-squares masked at the end.
__global__ __launch_bounds__(1024, 4) void fused_kernel(const float* __restrict__ W,
                                                        const float* __restrict__ x,
                                                        const float* __restrict__ heights,
                                                        float* __restrict__ out,
                                                        float* __restrict__ delta_out) {
    const int bid  = blockIdx.x;
    const int m    = ((bid & 7) << 5) | (bid >> 3);   // XCD-chunked bijection (256 = 8 XCD * 32)
    const int tid  = threadIdx.x;
    const int lane = tid & 63;
    const int wv   = tid >> 6;          // 0..15 : f-range [8*wv, 8*wv+8)
    const int j2   = lane;              // column pair (2*j2, 2*j2+1)

    int path[9];
    {
        int n = 255 + m;
#pragma unroll
        for (int k = 0; k < 9; ++k) { path[k] = n; n = (n - 1) >> 1; }
    }
    const float* R[15];
#pragma unroll
    for (int k = 0; k < 9; ++k) R[k] = W + (size_t)path[k] * DD;
    const int n9a = 511 + 2 * m, n9b = n9a + 1;
    R[9]  = W + (size_t)n9a * DD;
    R[10] = W + (size_t)n9b * DD;
#pragma unroll
    for (int q = 0; q < 4; ++q) R[11 + q] = W + (size_t)(1023 + 4 * m + q) * DD;

    float wgt[15];
#pragma unroll
    for (int k = 0; k < 8; ++k)
        wgt[k] = ((m & ((1 << k) - 1)) == 0) ? invmut(heights, path[k], path[k + 1]) : 0.f;
    wgt[8]  = 0.f;                       // root: no l1 term (sum-of-squares instead)
    wgt[9]  = invmut(heights, n9a, path[0]);
    wgt[10] = invmut(heights, n9b, path[0]);
#pragma unroll
    for (int q = 0; q < 4; ++q)
        wgt[11 + q] = invmut(heights, 1023 + 4 * m + q, (q < 2) ? n9a : n9b);
    const float sqmask = (m == 0) ? 1.f : 0.f;

    __shared__ float ins[4][HH];         // current layer input per leaf
    __shared__ float part[4][16][HH];    // matvec partials [leaf][wave][col]  (32 KB)
    __shared__ float lgts[4][CC];
    __shared__ float red[16];

    if (tid < 512) { const int q = tid >> 7, t = tid & 127; ins[q][t] = x[(4 * m + q) * FF + t]; }
    if (tid < 4 * CC) ((float*)lgts)[tid] = 0.f;

    float dacc = 0.f, sacc = 0.f;
    __syncthreads();

    // ---------------- layers 0 and 1 (128 -> 128) ----------------
#pragma unroll
    for (int layer = 0; layer < 2; ++layer) {
        const int offW = layer ? OFF_W1 : OFF_W0;
        const int offB = layer ? OFF_B1 : OFF_B0;
        const float2* S2[15];
#pragma unroll
        for (int r = 0; r < 15; ++r) S2[r] = reinterpret_cast<const float2*>(R[r] + offW);

        float yx[4], yy[4];
#pragma unroll
        for (int q = 0; q < 4; ++q) { yx[q] = 0.f; yy[q] = 0.f; }

#pragma unroll 2
        for (int i = 0; i < 8; ++i) {
            const int f   = (wv << 3) + i;
            const int off = (f << 6) + j2;
            float ex = 0.f, ey = 0.f;
#pragma unroll
            for (int k = 0; k < 9; ++k) {
                const float2 w = S2[k][off];
                ex += w.x; ey += w.y;
                dacc += (fabsf(w.x) + fabsf(w.y)) * wgt[k];
                if (k == 8) sacc += w.x * w.x + w.y * w.y;
            }
            const float2 wa0 = S2[9][off];
            const float2 wa1 = S2[10][off];
            dacc += (fabsf(wa0.x) + fabsf(wa0.y)) * wgt[9];
            dacc += (fabsf(wa1.x) + fabsf(wa1.y)) * wgt[10];
#pragma unroll
            for (int q = 0; q < 4; ++q) {
                const float2 wb = S2[11 + q][off];
                dacc += (fabsf(wb.x) + fabsf(wb.y)) * wgt[11 + q];
                const float2 wa = (q < 2) ? wa0 : wa1;
                const float xv = ins[q][f];
                yx[q] += xv * (ex + wa.x + wb.x);
                yy[q] += xv * (ey + wa.y + wb.y);
            }
        }
#pragma unroll
        for (int q = 0; q < 4; ++q)
            *reinterpret_cast<float2*>(&part[q][wv][2 * j2]) = make_float2(yx[q], yy[q]);
        __syncthreads();

        if (tid < 512) {
            const int q = tid >> 7, col = tid & 127;   // q uniform per wave
            float eb = 0.f;
#pragma unroll
            for (int k = 0; k < 9; ++k) {
                const float v = R[k][offB + col];
                eb += v;
                if (q == 0) { dacc += fabsf(v) * wgt[k]; if (k == 8) sacc += v * v; }
            }
            const float a0 = R[9][offB + col];
            const float a1 = R[10][offB + col];
            if (q == 0) dacc += fabsf(a0) * wgt[9];
            if (q == 2) dacc += fabsf(a1) * wgt[10];
            const float bq = R[11 + q][offB + col];
            dacc += fabsf(bq) * wgt[11 + q];
            float s = eb + ((q < 2) ? a0 : a1) + bq;
#pragma unroll
            for (int w = 0; w < 16; ++w) s += part[q][w][col];
            ins[q][col] = fmaxf(s, 0.f);
        }
        __syncthreads();
    }

    // ---------------- layer 2 (128 -> 10) ----------------
    {
        const float2* S2[15];
#pragma unroll
        for (int r = 0; r < 15; ++r) S2[r] = reinterpret_cast<const float2*>(R[r] + OFF_W2);
        if (tid < 640) {                 // 640 float2 = 1280 weights per row
            const int h  = tid / 5;
            const int c0 = (tid - 5 * h) * 2;
            float ex = 0.f, ey = 0.f;
#pragma unroll
            for (int k = 0; k < 9; ++k) {
                const float2 w = S2[k][tid];
                ex += w.x; ey += w.y;
                dacc += (fabsf(w.x) + fabsf(w.y)) * wgt[k];
                if (k == 8) sacc += w.x * w.x + w.y * w.y;
            }
            const float2 wa0 = S2[9][tid];
            const float2 wa1 = S2[10][tid];
            dacc += (fabsf(wa0.x) + fabsf(wa0.y)) * wgt[9];
            dacc += (fabsf(wa1.x) + fabsf(wa1.y)) * wgt[10];
#pragma unroll
            for (int q = 0; q < 4; ++q) {
                const float2 wb = S2[11 + q][tid];
                dacc += (fabsf(wb.x) + fabsf(wb.y)) * wgt[11 + q];
                const float2 wa = (q < 2) ? wa0 : wa1;
                const float hv = ins[q][h];
                atomicAdd(&lgts[q][c0],     hv * (ex + wa.x + wb.x));
                atomicAdd(&lgts[q][c0 + 1], hv * (ey + wa.y + wb.y));
            }
        }
        __syncthreads();
        if (tid < CC) {
            float eb = 0.f;
#pragma unroll
            for (int k = 0; k < 9; ++k) {
                const float v = R[k][OFF_B2 + tid];
                eb += v;
                dacc += fabsf(v) * wgt[k];
                if (k == 8) sacc += v * v;
            }
            const float a0 = R[9][OFF_B2 + tid];
            const float a1 = R[10][OFF_B2 + tid];
            dacc += fabsf(a0) * wgt[9] + fabsf(a1) * wgt[10];
#pragma unroll
            for (int q = 0; q < 4; ++q) {
                const float bq = R[11 + q][OFF_B2 + tid];
                dacc += fabsf(bq) * wgt[11 + q];
                lgts[q][tid] += eb + ((q < 2) ? a0 : a1) + bq;
            }
        }
        __syncthreads();
    }

    // ---------------- softmax (one thread per leaf) ----------------
    if (tid < 4) {
        const int q = tid;
        float mx = lgts[q][0];
#pragma unroll
        for (int c = 1; c < CC; ++c) mx = fmaxf(mx, lgts[q][c]);
        float e[CC], s = 0.f;
#pragma unroll
        for (int c = 0; c < CC; ++c) { e[c] = expf(lgts[q][c] - mx); s += e[c]; }
        const float inv = 1.f / s;
#pragma unroll
        for (int c = 0; c < CC; ++c) out[(4 * m + q) * CC + c] = e[c] * inv;
    }

    // ---------------- delta reduce: one weighted accumulator ----------------
    float v = dacc + sacc * sqmask;
    for (int o = 32; o > 0; o >>= 1) v += __shfl_down(v, o);
    if (lane == 0) red[wv] = v;
    __syncthreads();
    if (tid == 0) {
        float s = 0.f;
#pragma unroll
        for (int w = 0; w < 16; ++w) s += red[w];
        atomicAdd(delta_out, s);
    }
}

extern "C" void kernel_launch(void* const* d_in, const int* in_sizes, int n_in,
                              void* d_out, int out_size, void* d_ws, size_t ws_size,
                              hipStream_t stream) {
    const float* x       = (const float*)d_in[0];   // (1024, 128)
    const float* W       = (const float*)d_in[1];   // (2047, 34314)
    const float* heights = (const float*)d_in[2];   // (2047,)

    float* out   = (float*)d_out;
    float* delta = (float*)d_out + LN * CC;

    init_delta<<<1, 1, 0, stream>>>(delta);
    fused_kernel<<<256, 1024, 0, stream>>>(W, x, heights, out, delta);
}